// Round 24
// baseline (102.279 us; speedup 1.0000x reference)
//
#include <hip/hip_runtime.h>

#define HID 50
#define TSTEPS 512

typedef _Float16 h2v __attribute__((ext_vector_type(2)));

__device__ __forceinline__ float fdot2(h2v a, h2v b, float c) {
#if __has_builtin(__builtin_amdgcn_fdot2)
    return __builtin_amdgcn_fdot2(a, b, c, false);
#else
    asm("v_dot2_f32_f16 %0, %1, %2, %0" : "+v"(c) : "v"(a), "v"(b));
    return c;
#endif
}
__device__ __forceinline__ h2v bits_to_h2(unsigned u) {
    h2v r; __builtin_memcpy(&r, &u, sizeof(r)); return r;
}
#define SGB __builtin_amdgcn_sched_group_barrier

// R22 minus stagger (proven neutral) + LDS-burst spreading via
// sched_group_barrier (T19).
// Accounting: wall 508cy/step = per-wave CHAIN (VALUBusy 65% == 2x165/508:
// both waves already issue fully; chain-bound, not issue-bound). Nominal
// chain ~300cy; the extra ~200 = bursty LDS-queue congestion: 7 quad-reads
// issued back-to-back x 8 waves/CU -> ~70-deep queue bursts -> last return
// (needed by the dot tail) delayed ~150-200cy. Fix: interleave
// {1 ds_read | 4 dot2} so reads enter the queue ~10cy apart; SGB pins the
// pattern (compiler's default is to re-hoist loads into a burst).
// Same arithmetic order -> bit-identical result to R16/R21/R22.
__global__ __launch_bounds__(64) __attribute__((amdgpu_waves_per_eu(2, 2)))
void rnn_fused(
    const float* __restrict__ x,      // [B, 512, 1]
    const float* __restrict__ W_ih,   // [50, 1]
    const float* __restrict__ W_hh,   // [50, 50]
    const float* __restrict__ b_ih,   // [50]
    const float* __restrict__ b_hh,   // [50]
    const float* __restrict__ W_fc,   // [1, 50]
    const float* __restrict__ b_fc,   // [1]
    float* __restrict__ out)          // [B, 1]
{
    const int b = blockIdx.x;
    const int j = threadIdx.x;        // 0..63; lanes 50..63 only stage x
    __shared__ __align__(16) _Float16 hht[64];   // h table; slots 50..63 = 0
    __shared__ __align__(16) float xbuf[64];

    const int jj = (j < HID) ? j : 0;
    const float SC = 2.8853900817779268f;   // 2*log2(e)

    h2v w2[25];
#pragma unroll
    for (int m = 0; m < 25; ++m) {
        h2v t;
        t.x = (_Float16)(W_hh[jj * HID + 2 * m]     * SC);
        t.y = (_Float16)(W_hh[jj * HID + 2 * m + 1] * SC);
        w2[m] = t;
    }
    const float wih  = W_ih[jj] * SC;
    const float btot = (b_ih[jj] + b_hh[jj]) * SC;
    const float wfc  = (j < HID) ? W_fc[jj] : 0.0f;
    const float bfc  = b_fc[0];

    const float* xb = x + (size_t)b * TSTEPS;
    float xv = xb[j];                 // 64 timesteps of x, one per lane
    float hn = 0.0f;
    hht[j] = (_Float16)0.0f;          // h0 = 0 (slots 50..63 stay 0 forever)
    // no barrier: same-wave in-order DS covers write->read (R18/R19-proven)

    for (int c = 0; c < TSTEPS / 64; ++c) {
        xbuf[j] = xv;                 // staged by all 64 lanes, in-order DS
        float xv_next = 0.0f;
        if (c + 1 < TSTEPS / 64) xv_next = xb[(c + 1) * 64 + j];

        if (j < HID) {                // one exec-mask toggle per 64 steps
            for (int g = 0; g < 8; ++g) {
#pragma unroll
                for (int ii = 0; ii < 8; ++ii) {
                    const int t = g * 8 + ii;
                    const uint4* h8 = reinterpret_cast<const uint4*>(hht);

                    // ---- write + lead loads (prio 0)
                    __builtin_amdgcn_s_setprio(0);
                    hht[j] = (_Float16)hn;
                    const float xt = xbuf[t];
                    uint4 u0 = h8[0];
                    uint4 u1 = h8[1];
                    SGB(0x200, 1, 0);             // 1 ds_write
                    SGB(0x100, 3, 0);             // xt, u0, u1

                    // ---- spread phase: {4 dot2 | 1 ds_read} x 5 (prio 1)
                    __builtin_amdgcn_s_setprio(1);
                    float a0 = btot, a1 = 0.f, a2 = 0.f, a3 = 0.f;
                    a0 = fdot2(bits_to_h2(u0.x), w2[0],  a0);
                    a1 = fdot2(bits_to_h2(u0.y), w2[1],  a1);
                    a2 = fdot2(bits_to_h2(u0.z), w2[2],  a2);
                    a3 = fdot2(bits_to_h2(u0.w), w2[3],  a3);
                    uint4 u2 = h8[2];
                    SGB(0x2, 4, 0); SGB(0x100, 1, 0);
                    a0 = fdot2(bits_to_h2(u1.x), w2[4],  a0);
                    a1 = fdot2(bits_to_h2(u1.y), w2[5],  a1);
                    a2 = fdot2(bits_to_h2(u1.z), w2[6],  a2);
                    a3 = fdot2(bits_to_h2(u1.w), w2[7],  a3);
                    uint4 u3 = h8[3];
                    SGB(0x2, 4, 0); SGB(0x100, 1, 0);
                    a0 = fdot2(bits_to_h2(u2.x), w2[8],  a0);
                    a1 = fdot2(bits_to_h2(u2.y), w2[9],  a1);
                    a2 = fdot2(bits_to_h2(u2.z), w2[10], a2);
                    a3 = fdot2(bits_to_h2(u2.w), w2[11], a3);
                    uint4 u4 = h8[4];
                    SGB(0x2, 4, 0); SGB(0x100, 1, 0);
                    a0 = fdot2(bits_to_h2(u3.x), w2[12], a0);
                    a1 = fdot2(bits_to_h2(u3.y), w2[13], a1);
                    a2 = fdot2(bits_to_h2(u3.z), w2[14], a2);
                    a3 = fdot2(bits_to_h2(u3.w), w2[15], a3);
                    uint4 u5 = h8[5];
                    SGB(0x2, 4, 0); SGB(0x100, 1, 0);
                    a0 = fdot2(bits_to_h2(u4.x), w2[16], a0);
                    a1 = fdot2(bits_to_h2(u4.y), w2[17], a1);
                    a2 = fdot2(bits_to_h2(u4.z), w2[18], a2);
                    a3 = fdot2(bits_to_h2(u4.w), w2[19], a3);
                    uint4 u6 = h8[6];
                    SGB(0x2, 4, 0); SGB(0x100, 1, 0);
                    a0 = fdot2(bits_to_h2(u5.x), w2[20], a0);
                    a1 = fdot2(bits_to_h2(u5.y), w2[21], a1);
                    a2 = fdot2(bits_to_h2(u5.z), w2[22], a2);
                    a3 = fdot2(bits_to_h2(u5.w), w2[23], a3);
                    a0 = fdot2(bits_to_h2(u6.x), w2[24], a0);
                    const float z = fmaf(xt, wih, (a0 + a1) + (a2 + a3));

                    // tanh(s) = 1 - 2/(exp2(z)+1); saturates at +-inf
                    const float e = __builtin_amdgcn_exp2f(z);
                    const float r = __builtin_amdgcn_rcpf(e + 1.0f);
                    hn = fmaf(-2.0f, r, 1.0f);

                    __builtin_amdgcn_sched_barrier(0);  // pin step boundary
                }
            }
        }
        xv = xv_next;
    }
    __builtin_amdgcn_s_setprio(0);

    // out[b] = sum_j h_T[j]*W_fc[j] + b_fc (lanes >= 50: hn=0, wfc=0)
    float pr = hn * wfc;
#pragma unroll
    for (int off = 32; off >= 1; off >>= 1) pr += __shfl_xor(pr, off);
    if (j == 0) out[b] = pr + bfc;
}

extern "C" void kernel_launch(void* const* d_in, const int* in_sizes, int n_in,
                              void* d_out, int out_size, void* d_ws, size_t ws_size,
                              hipStream_t stream) {
    (void)d_ws; (void)ws_size; (void)n_in; (void)out_size;
    const float* x    = (const float*)d_in[0];
    const float* W_ih = (const float*)d_in[1];
    const float* W_hh = (const float*)d_in[2];
    const float* b_ih = (const float*)d_in[3];
    const float* b_hh = (const float*)d_in[4];
    const float* W_fc = (const float*)d_in[5];
    const float* b_fc = (const float*)d_in[6];
    float* out = (float*)d_out;

    const int B = in_sizes[0] / TSTEPS;   // 2048
    rnn_fused<<<dim3(B), dim3(64), 0, stream>>>(x, W_ih, W_hh, b_ih, b_hh,
                                                W_fc, b_fc, out);
}

// Round 27
// 99.695 us; speedup vs baseline: 1.0259x; 1.0259x over previous
//
#include <hip/hip_runtime.h>

#define HID 50
#define TSTEPS 512

typedef _Float16 h2v __attribute__((ext_vector_type(2)));

__device__ __forceinline__ float fdot2(h2v a, h2v b, float c) {
#if __has_builtin(__builtin_amdgcn_fdot2)
    return __builtin_amdgcn_fdot2(a, b, c, false);
#else
    asm("v_dot2_f32_f16 %0, %1, %2, %0" : "+v"(c) : "v"(a), "v"(b));
    return c;
#endif
}
__device__ __forceinline__ h2v bits_to_h2(unsigned u) {
    h2v r; __builtin_memcpy(&r, &u, sizeof(r)); return r;
}

// RESTORE of the session best (R22 measurement: 99.7us bench / 108.3 rocprof).
// R21 + s_setprio phase split (the only scheduling lever that measured real:
// +4%). Structure: 1 batch/wave, fp16 h table in LDS, broadcast = 7x
// ds_read_b128, dot = 25 v_dot2_f32_f16, barrier-free (same-wave in-order DS,
// proven R18/R19), recurrence predicated to 50 lanes.
// Post-R26 status: asm counted-wait pipeline corrupts data (async ds_read
// outputs + regalloc copies); depth-2 in-wave overlap unreachable at HIP
// level; chain ~508cy/step-pair irreducible by barriers/traffic/stagger/SGB.
__global__ __launch_bounds__(64) __attribute__((amdgpu_waves_per_eu(2, 2)))
void rnn_fused(
    const float* __restrict__ x,      // [B, 512, 1]
    const float* __restrict__ W_ih,   // [50, 1]
    const float* __restrict__ W_hh,   // [50, 50]
    const float* __restrict__ b_ih,   // [50]
    const float* __restrict__ b_hh,   // [50]
    const float* __restrict__ W_fc,   // [1, 50]
    const float* __restrict__ b_fc,   // [1]
    float* __restrict__ out)          // [B, 1]
{
    const int b = blockIdx.x;
    const int j = threadIdx.x;        // 0..63; lanes 50..63 only stage x
    __shared__ __align__(16) _Float16 hht[64];   // h table; slots 50..63 = 0
    __shared__ __align__(16) float xbuf[64];

    const int jj = (j < HID) ? j : 0;
    const float SC = 2.8853900817779268f;   // 2*log2(e)

    h2v w2[25];
#pragma unroll
    for (int m = 0; m < 25; ++m) {
        h2v t;
        t.x = (_Float16)(W_hh[jj * HID + 2 * m]     * SC);
        t.y = (_Float16)(W_hh[jj * HID + 2 * m + 1] * SC);
        w2[m] = t;
    }
    const float wih  = W_ih[jj] * SC;
    const float btot = (b_ih[jj] + b_hh[jj]) * SC;
    const float wfc  = (j < HID) ? W_fc[jj] : 0.0f;
    const float bfc  = b_fc[0];

    const float* xb = x + (size_t)b * TSTEPS;
    float xv = xb[j];                 // 64 timesteps of x, one per lane
    float hn = 0.0f;
    hht[j] = (_Float16)0.0f;          // h0 = 0 (slots 50..63 stay 0 forever)
    // no barrier: same-wave in-order DS covers write->read (R18/R19-proven)

    for (int c = 0; c < TSTEPS / 64; ++c) {
        xbuf[j] = xv;                 // staged by all 64 lanes, in-order DS
        float xv_next = 0.0f;
        if (c + 1 < TSTEPS / 64) xv_next = xb[(c + 1) * 64 + j];

        if (j < HID) {                // one exec-mask toggle per 64 steps
            for (int g = 0; g < 8; ++g) {
#pragma unroll
                for (int ii = 0; ii < 8; ++ii) {
                    const int t = g * 8 + ii;

                    // ---- memory-issue phase at prio 0
                    __builtin_amdgcn_s_setprio(0);
                    hht[j] = (_Float16)hn;        // write first: queues ahead
                    const float xt = xbuf[t];     // of the reads below
                    const uint4* h8 = reinterpret_cast<const uint4*>(hht);
                    uint4 u0 = h8[0], u1 = h8[1], u2 = h8[2], u3 = h8[3],
                          u4 = h8[4], u5 = h8[5], u6 = h8[6];

                    // ---- compute phase at prio 1 (prio latched across the
                    //      auto-waitcnt stall; a computing wave outprioritizes
                    //      the other wave's read burst -> anti-phase)
                    __builtin_amdgcn_s_setprio(1);
                    float a0 = btot, a1 = 0.f, a2 = 0.f, a3 = 0.f;
                    a0 = fdot2(bits_to_h2(u0.x), w2[0],  a0);
                    a1 = fdot2(bits_to_h2(u0.y), w2[1],  a1);
                    a2 = fdot2(bits_to_h2(u0.z), w2[2],  a2);
                    a3 = fdot2(bits_to_h2(u0.w), w2[3],  a3);
                    a0 = fdot2(bits_to_h2(u1.x), w2[4],  a0);
                    a1 = fdot2(bits_to_h2(u1.y), w2[5],  a1);
                    a2 = fdot2(bits_to_h2(u1.z), w2[6],  a2);
                    a3 = fdot2(bits_to_h2(u1.w), w2[7],  a3);
                    a0 = fdot2(bits_to_h2(u2.x), w2[8],  a0);
                    a1 = fdot2(bits_to_h2(u2.y), w2[9],  a1);
                    a2 = fdot2(bits_to_h2(u2.z), w2[10], a2);
                    a3 = fdot2(bits_to_h2(u2.w), w2[11], a3);
                    a0 = fdot2(bits_to_h2(u3.x), w2[12], a0);
                    a1 = fdot2(bits_to_h2(u3.y), w2[13], a1);
                    a2 = fdot2(bits_to_h2(u3.z), w2[14], a2);
                    a3 = fdot2(bits_to_h2(u3.w), w2[15], a3);
                    a0 = fdot2(bits_to_h2(u4.x), w2[16], a0);
                    a1 = fdot2(bits_to_h2(u4.y), w2[17], a1);
                    a2 = fdot2(bits_to_h2(u4.z), w2[18], a2);
                    a3 = fdot2(bits_to_h2(u4.w), w2[19], a3);
                    a0 = fdot2(bits_to_h2(u5.x), w2[20], a0);
                    a1 = fdot2(bits_to_h2(u5.y), w2[21], a1);
                    a2 = fdot2(bits_to_h2(u5.z), w2[22], a2);
                    a3 = fdot2(bits_to_h2(u5.w), w2[23], a3);
                    a0 = fdot2(bits_to_h2(u6.x), w2[24], a0);
                    const float z = fmaf(xt, wih, (a0 + a1) + (a2 + a3));

                    // tanh(s) = 1 - 2/(exp2(z)+1); saturates at +-inf
                    const float e = __builtin_amdgcn_exp2f(z);
                    const float r = __builtin_amdgcn_rcpf(e + 1.0f);
                    hn = fmaf(-2.0f, r, 1.0f);

                    __builtin_amdgcn_sched_barrier(0);  // pin step boundary
                }
            }
        }
        xv = xv_next;
    }
    __builtin_amdgcn_s_setprio(0);

    // out[b] = sum_j h_T[j]*W_fc[j] + b_fc (lanes >= 50: hn=0, wfc=0)
    float pr = hn * wfc;
#pragma unroll
    for (int off = 32; off >= 1; off >>= 1) pr += __shfl_xor(pr, off);
    if (j == 0) out[b] = pr + bfc;
}

extern "C" void kernel_launch(void* const* d_in, const int* in_sizes, int n_in,
                              void* d_out, int out_size, void* d_ws, size_t ws_size,
                              hipStream_t stream) {
    (void)d_ws; (void)ws_size; (void)n_in; (void)out_size;
    const float* x    = (const float*)d_in[0];
    const float* W_ih = (const float*)d_in[1];
    const float* W_hh = (const float*)d_in[2];
    const float* b_ih = (const float*)d_in[3];
    const float* b_hh = (const float*)d_in[4];
    const float* W_fc = (const float*)d_in[5];
    const float* b_fc = (const float*)d_in[6];
    float* out = (float*)d_out;

    const int B = in_sizes[0] / TSTEPS;   // 2048
    rnn_fused<<<dim3(B), dim3(64), 0, stream>>>(x, W_ih, W_hh, b_ih, b_hh,
                                                W_fc, b_fc, out);
}